// Round 8
// baseline (1253.271 us; speedup 1.0000x reference)
//
#include <hip/hip_runtime.h>

// ---------------------------------------------------------------------------
// CapsuleNetwork: embedding -> 2-layer BiLSTM -> attn pooling -> routing
// Round 7: fwd+bwd chains merged into one block (dual-pipeline): while one
// direction's publish/poll latency drains, the other direction computes.
//  - 256 blocks x 512 thr (1/CU); W for BOTH dirs in VGPR (128 regs).
//  - interleaved k-assignment (k = i*8+ks): conflict-free hbuf b128 reads.
//  - hx stored [dim][4b]: staging is a linear coalesced copy.
//  - all-thread flag polling (no single-lane poll + extra barrier).
// B=128 T=64 E=300 H=256 DA=128 R=8 SC=32 AT=16
// ---------------------------------------------------------------------------

__device__ __forceinline__ float sigf(float x) { return 1.0f / (1.0f + __expf(-x)); }
__device__ __forceinline__ float tanhf_fast(float x) { return 1.0f - 2.0f / (__expf(2.0f * x) + 1.0f); }

#define DPPF(v, ctrl) __int_as_float(__builtin_amdgcn_update_dpp(0, __float_as_int(v), ctrl, 0xF, 0xF, true))

// ---------------- transpose w_hh [1024][256] -> Wt [256][1024] -------------
__global__ void k_transpose(const float* __restrict__ w0, const float* __restrict__ w1,
                            const float* __restrict__ w2, const float* __restrict__ w3,
                            float* __restrict__ wt)
{
    __shared__ float tile[32][33];
    const float* W = (blockIdx.z == 0) ? w0 : (blockIdx.z == 1) ? w1 : (blockIdx.z == 2) ? w2 : w3;
    float* Wt = wt + (size_t)blockIdx.z * 256 * 1024;
    const int j0 = blockIdx.x * 32, k0 = blockIdx.y * 32;
    const int tx = threadIdx.x, ty = threadIdx.y;  // (32,8)
    #pragma unroll
    for (int i = 0; i < 32; i += 8)
        tile[ty + i][tx] = W[(size_t)(j0 + ty + i) * 256 + (k0 + tx)];
    __syncthreads();
    #pragma unroll
    for (int i = 0; i < 32; i += 8)
        Wt[(size_t)(k0 + ty + i) * 1024 + (j0 + tx)] = tile[tx][ty + i];
}

// ---------------- zero sync flags ------------------------------------------
__global__ void k_zero(int* __restrict__ p, int n)
{
    const int i = blockIdx.x * blockDim.x + threadIdx.x;
    if (i < n) p[i] = 0;
}

// ---------------- fp32 GEMM, BK=32, reg-double-buffered (R6) ---------------
__global__ __launch_bounds__(256) void k_gemm(
    const float* __restrict__ A, int lda, const int* __restrict__ tokens,
    const float* __restrict__ W0, const float* __restrict__ W1, int nsplit, int ldw,
    const float* __restrict__ bias0, const float* __restrict__ bias1,
    float* __restrict__ C, int ldc, int K, int transb, int act_tanh,
    long long sA, long long sW, long long sC)
{
    __shared__ float As[32][128];
    __shared__ float Ws[32][128];
    A  += (size_t)blockIdx.z * (size_t)sA;
    W0 += (size_t)blockIdx.z * (size_t)sW;
    C  += (size_t)blockIdx.z * (size_t)sC;
    const int tid = threadIdx.x;
    const int m0 = blockIdx.x * 128;
    const int n0 = blockIdx.y * 128;

    const int srow = tid >> 1;
    const int kh   = (tid & 1) * 16;
    const int am = m0 + srow;
    const float* arow;
    if (tokens) {
        const int t = am >> 7, b = am & 127;
        arow = A + (size_t)tokens[b * 64 + t] * lda;
    } else {
        arow = A + (size_t)am * lda;
    }
    const int wn = n0 + srow;
    const float* wrow = (wn < nsplit) ? (W0 + (size_t)wn * ldw)
                                      : (W1 + (size_t)(wn - nsplit) * ldw);
    const int kw = tid >> 3;
    const int n8 = (tid & 7) * 16;

    const int tm4 = (tid & 15) * 4;
    const int tn4 = (tid >> 4) * 4;
    float acc[8][8] = {};
    float4 ra[4], rw[4];

    const int nt = (K + 31) / 32;

    #pragma unroll
    for (int j = 0; j < 4; ++j) {
        const int k = kh + j * 4;
        if (k + 3 < K) ra[j] = *(const float4*)(arow + k);
        else {
            float t0 = (k + 0 < K) ? arow[k + 0] : 0.f;
            float t1 = (k + 1 < K) ? arow[k + 1] : 0.f;
            float t2 = (k + 2 < K) ? arow[k + 2] : 0.f;
            float t3 = (k + 3 < K) ? arow[k + 3] : 0.f;
            ra[j] = make_float4(t0, t1, t2, t3);
        }
    }
    if (transb) {
        #pragma unroll
        for (int j = 0; j < 4; ++j) {
            const int k = kh + j * 4;
            if (k + 3 < K) rw[j] = *(const float4*)(wrow + k);
            else {
                float t0 = (k + 0 < K) ? wrow[k + 0] : 0.f;
                float t1 = (k + 1 < K) ? wrow[k + 1] : 0.f;
                float t2 = (k + 2 < K) ? wrow[k + 2] : 0.f;
                float t3 = (k + 3 < K) ? wrow[k + 3] : 0.f;
                rw[j] = make_float4(t0, t1, t2, t3);
            }
        }
    } else {
        const float* src = (kw < K) ? (W0 + (size_t)kw * ldw + n0 + n8) : W0;
        #pragma unroll
        for (int j = 0; j < 4; ++j)
            rw[j] = (kw < K) ? *(const float4*)(src + j * 4) : make_float4(0, 0, 0, 0);
    }

    for (int tile = 0; tile < nt; ++tile) {
        #pragma unroll
        for (int j = 0; j < 4; ++j) {
            As[kh + j * 4 + 0][srow] = ra[j].x;
            As[kh + j * 4 + 1][srow] = ra[j].y;
            As[kh + j * 4 + 2][srow] = ra[j].z;
            As[kh + j * 4 + 3][srow] = ra[j].w;
        }
        if (transb) {
            #pragma unroll
            for (int j = 0; j < 4; ++j) {
                Ws[kh + j * 4 + 0][srow] = rw[j].x;
                Ws[kh + j * 4 + 1][srow] = rw[j].y;
                Ws[kh + j * 4 + 2][srow] = rw[j].z;
                Ws[kh + j * 4 + 3][srow] = rw[j].w;
            }
        } else {
            #pragma unroll
            for (int j = 0; j < 4; ++j)
                *(float4*)&Ws[kw][n8 + j * 4] = rw[j];
        }
        __syncthreads();
        if (tile + 1 < nt) {
            const int kb = (tile + 1) * 32;
            #pragma unroll
            for (int j = 0; j < 4; ++j) {
                const int k = kb + kh + j * 4;
                if (k + 3 < K) ra[j] = *(const float4*)(arow + k);
                else {
                    float t0 = (k + 0 < K) ? arow[k + 0] : 0.f;
                    float t1 = (k + 1 < K) ? arow[k + 1] : 0.f;
                    float t2 = (k + 2 < K) ? arow[k + 2] : 0.f;
                    float t3 = (k + 3 < K) ? arow[k + 3] : 0.f;
                    ra[j] = make_float4(t0, t1, t2, t3);
                }
            }
            if (transb) {
                #pragma unroll
                for (int j = 0; j < 4; ++j) {
                    const int k = kb + kh + j * 4;
                    if (k + 3 < K) rw[j] = *(const float4*)(wrow + k);
                    else {
                        float t0 = (k + 0 < K) ? wrow[k + 0] : 0.f;
                        float t1 = (k + 1 < K) ? wrow[k + 1] : 0.f;
                        float t2 = (k + 2 < K) ? wrow[k + 2] : 0.f;
                        float t3 = (k + 3 < K) ? wrow[k + 3] : 0.f;
                        rw[j] = make_float4(t0, t1, t2, t3);
                    }
                }
            } else {
                const int k = kb + kw;
                const float* src = (k < K) ? (W0 + (size_t)k * ldw + n0 + n8) : W0;
                #pragma unroll
                for (int j = 0; j < 4; ++j)
                    rw[j] = (k < K) ? *(const float4*)(src + j * 4) : make_float4(0, 0, 0, 0);
            }
        }
        #pragma unroll 8
        for (int kk = 0; kk < 32; ++kk) {
            const float4 a0 = *(const float4*)&As[kk][tm4];
            const float4 a1 = *(const float4*)&As[kk][tm4 + 64];
            const float4 b0 = *(const float4*)&Ws[kk][tn4];
            const float4 b1 = *(const float4*)&Ws[kk][tn4 + 64];
            const float av[8] = {a0.x, a0.y, a0.z, a0.w, a1.x, a1.y, a1.z, a1.w};
            const float bv[8] = {b0.x, b0.y, b0.z, b0.w, b1.x, b1.y, b1.z, b1.w};
            #pragma unroll
            for (int i = 0; i < 8; ++i)
                #pragma unroll
                for (int j = 0; j < 8; ++j)
                    acc[i][j] += av[i] * bv[j];
        }
        __syncthreads();
    }
    const int half = (n0 >= nsplit) ? 1 : 0;
    const float* bp = half ? bias1 : bias0;
    const int nl = n0 - (half ? nsplit : 0);
    #pragma unroll
    for (int i = 0; i < 8; ++i) {
        const int row = m0 + tm4 + (i >> 2) * 64 + (i & 3);
        #pragma unroll
        for (int jh = 0; jh < 2; ++jh) {
            float v[4];
            #pragma unroll
            for (int j = 0; j < 4; ++j) {
                float x = acc[i][jh * 4 + j];
                if (bp) x += bp[nl + tn4 + jh * 64 + j];
                if (act_tanh) x = tanhf_fast(x);
                v[j] = x;
            }
            *(float4*)(C + (size_t)row * ldc + n0 + tn4 + jh * 64) =
                make_float4(v[0], v[1], v[2], v[3]);
        }
    }
}

// ---------------- BiLSTM scan: dual-direction pipeline ---------------------
// 256 blocks x 512 thr (1/CU). bx = s*32 + q: s = slice (32 h-dims), q =
// batch group (4 rows). Each block runs BOTH directions; per iteration:
// F-substep then B-substep. While one chain's publish propagates through the
// coherence point, the other chain computes -> sync latency off the critical
// path. hx layout [parity][dir][q][dim*4+b] so staging is a linear copy.
// Thread phase1: cg = tid>>3 (2 cols), ks = tid&7; k = i*8+ks (interleaved:
// the 8 ks-lanes read 8 consecutive float4s -> all 32 banks, conflict-free).
#define SUBSTEP(DIR, WARR, CSTATE, Z0, Z1, Z2, Z3)                                        \
    do {                                                                                  \
        const int t_ = (DIR) ? (63 - tt) : tt;                                            \
        const int fbase_ = ((DIR) * 32 + q) * 64;                                         \
        if (tt > 0) {                                                                     \
            while (__hip_atomic_load(&flags[fbase_ + tt - 1], __ATOMIC_RELAXED,           \
                                     __HIP_MEMORY_SCOPE_AGENT) < 8)                       \
                __builtin_amdgcn_s_sleep(2);                                              \
            const float* hsrc_ = hx + ((((size_t)((tt - 1) & 1)) * 2 + (DIR)) * 32 + q) * 1024; \
            hbuf[tid]       = __hip_atomic_load(&hsrc_[tid], __ATOMIC_RELAXED,            \
                                                __HIP_MEMORY_SCOPE_AGENT);                \
            hbuf[tid + 512] = __hip_atomic_load(&hsrc_[tid + 512], __ATOMIC_RELAXED,      \
                                                __HIP_MEMORY_SCOPE_AGENT);                \
            __syncthreads();                                                              \
            float acc[4][2] = {};                                                         \
            _Pragma("unroll")                                                             \
            for (int i = 0; i < 32; ++i) {                                                \
                const int k_ = i * 8 + ks;                                                \
                const float4 h4 = *(const float4*)&hbuf[k_ << 2];                         \
                acc[0][0] += h4.x * WARR[i][0]; acc[0][1] += h4.x * WARR[i][1];           \
                acc[1][0] += h4.y * WARR[i][0]; acc[1][1] += h4.y * WARR[i][1];           \
                acc[2][0] += h4.z * WARR[i][0]; acc[2][1] += h4.z * WARR[i][1];           \
                acc[3][0] += h4.w * WARR[i][0]; acc[3][1] += h4.w * WARR[i][1];           \
            }                                                                             \
            _Pragma("unroll")                                                             \
            for (int b = 0; b < 4; ++b)                                                   \
                _Pragma("unroll")                                                         \
                for (int c = 0; c < 2; ++c) {                                             \
                    float v = acc[b][c];                                                  \
                    v += DPPF(v, 0xB1);                                                   \
                    v += DPPF(v, 0x4E);                                                   \
                    v += DPPF(DPPF(v, 0x141), 0x1B);                                      \
                    acc[b][c] = v;                                                        \
                }                                                                         \
            _Pragma("unroll")                                                             \
            for (int a = 0; a < 8; ++a)                                                   \
                if (ks == a)                                                              \
                    zbuf[(a >> 1) * 128 + gate * 32 + wg * 2 + (a & 1)] = acc[a >> 1][a & 1]; \
            __syncthreads();                                                              \
        } else {                                                                          \
            zbuf[tid & 511] = 0.0f;                                                       \
            __syncthreads();                                                              \
        }                                                                                 \
        if (tid < 128) {                                                                  \
            const float zi = zbuf[pb * 128 +      pd] + (Z0);                             \
            const float zf = zbuf[pb * 128 + 32 + pd] + (Z1);                             \
            const float zg = zbuf[pb * 128 + 64 + pd] + (Z2);                             \
            const float zo = zbuf[pb * 128 + 96 + pd] + (Z3);                             \
            CSTATE = sigf(zf) * CSTATE + sigf(zi) * tanhf_fast(zg);                       \
            const float h_ = sigf(zo) * tanhf_fast(CSTATE);                               \
            const int row_ = bt_layout ? (gb * 64 + t_) : (t_ * 128 + gb);                \
            outbuf[(size_t)row_ * 512 + (DIR) * 256 + dim] = h_;                          \
            __hip_atomic_store(                                                           \
                &hx[(((size_t)(tt & 1)) * 2 + (DIR)) * 32768 + (size_t)q * 1024 + (dim << 2) + pb], \
                h_, __ATOMIC_RELAXED, __HIP_MEMORY_SCOPE_AGENT);                          \
        }                                                                                 \
        __syncthreads();                                                                  \
        if (tid == 0)                                                                     \
            __hip_atomic_fetch_add(&flags[fbase_ + tt], 1, __ATOMIC_RELAXED,              \
                                   __HIP_MEMORY_SCOPE_AGENT);                             \
    } while (0)

__global__ __launch_bounds__(512, 2) void k_scan5(
    const float* __restrict__ Zin, const float* __restrict__ WtF,
    const float* __restrict__ WtB, float* __restrict__ outbuf,
    int bt_layout, float* __restrict__ hx, int* __restrict__ flags)
{
    __shared__ __align__(16) float hbuf[1024];   // h as [dim][4b], linear
    __shared__ float zbuf[512];                  // [4b][128 local cols]

    const int bx  = blockIdx.x;
    const int s   = bx >> 5;           // 0..7 slice
    const int q   = bx & 31;           // batch group
    const int tid = threadIdx.x;
    const int cg  = tid >> 3;          // 0..63 col group (2 cols)
    const int ks  = tid & 7;           // 0..7  k lane
    const int gate = cg >> 4;          // 0..3
    const int wg   = cg & 15;          // 0..15
    const int colbase = gate * 256 + s * 32 + wg * 2;

    // ---- preload W slices for BOTH directions (once): 2 cols x 32 k ----
    float W_f[32][2], W_b[32][2];
    {
        const float* wpF = WtF + (size_t)ks * 1024 + colbase;
        const float* wpB = WtB + (size_t)ks * 1024 + colbase;
        #pragma unroll
        for (int i = 0; i < 32; ++i) {
            const float2 a = *(const float2*)(wpF + (size_t)i * 8192);
            const float2 b = *(const float2*)(wpB + (size_t)i * 8192);
            W_f[i][0] = a.x; W_f[i][1] = a.y;
            W_b[i][0] = b.x; W_b[i][1] = b.y;
        }
    }

    const int pb  = tid >> 5;          // batch 0..3   (phase2, tid<128)
    const int pd  = tid & 31;          // local dim
    const int dim = s * 32 + pd;
    const int gb  = q * 4 + pb;
    float c_f = 0.0f, c_b = 0.0f;

    for (int tt = 0; tt < 64; ++tt) {
        // prefetch Z for both substeps (independent of h)
        float zF0 = 0.f, zF1 = 0.f, zF2 = 0.f, zF3 = 0.f;
        float zB0 = 0.f, zB1 = 0.f, zB2 = 0.f, zB3 = 0.f;
        if (tid < 128) {
            const float* zrF = Zin + (size_t)(tt * 128 + gb) * 2048 + dim;
            zF0 = zrF[0]; zF1 = zrF[256]; zF2 = zrF[512]; zF3 = zrF[768];
            const float* zrB = Zin + (size_t)((63 - tt) * 128 + gb) * 2048 + 1024 + dim;
            zB0 = zrB[0]; zB1 = zrB[256]; zB2 = zrB[512]; zB3 = zrB[768];
        }
        SUBSTEP(0, W_f, c_f, zF0, zF1, zF2, zF3);
        SUBSTEP(1, W_b, c_b, zB0, zB1, zB2, zB3);
    }
}

// ---------------- attention pooling (unchanged) ----------------------------
__global__ __launch_bounds__(256) void k_attnpool(
    const float* __restrict__ hbar, const float* __restrict__ outp,
    const float* __restrict__ ws2, float* __restrict__ sent)
{
    __shared__ float hb[64][132];
    __shared__ float w2[8][128];
    __shared__ float att[8][64];
    const int b = blockIdx.x, tid = threadIdx.x;
    for (int i = tid; i < 1024; i += 256) ((float*)w2)[i] = ws2[i];
    const float* hsrc = hbar + (size_t)b * 64 * 128;
    for (int i = tid; i < 2048; i += 256) {
        const int row = i >> 5, d4 = (i & 31) << 2;
        *(float4*)&hb[row][d4] = *(const float4*)(hsrc + row * 128 + d4);
    }
    __syncthreads();
    for (int p = tid; p < 512; p += 256) {
        const int r = p >> 6, t = p & 63;
        float s = 0.0f;
        #pragma unroll 8
        for (int d = 0; d < 128; d += 4) {
            const float4 x = *(const float4*)&hb[t][d];
            const float4 y = *(const float4*)&w2[r][d];
            s += x.x * y.x + x.y * y.y + x.z * y.z + x.w * y.w;
        }
        att[r][t] = s;
    }
    __syncthreads();
    const float* ob = outp + (size_t)b * 64 * 512;
    float s0[8] = {}, s1[8] = {};
    for (int t = 0; t < 64; ++t) {
        const float v0 = ob[t * 512 + tid];
        const float v1 = ob[t * 512 + 256 + tid];
        #pragma unroll
        for (int r = 0; r < 8; ++r) {
            const float a = att[r][t];
            s0[r] += a * v0; s1[r] += a * v1;
        }
    }
    #pragma unroll
    for (int r = 0; r < 8; ++r) {
        sent[((size_t)b * 8 + r) * 512 + tid]       = s0[r];
        sent[((size_t)b * 8 + r) * 512 + 256 + tid] = s1[r];
    }
}

// ---------------- dynamic routing (unchanged) ------------------------------
__global__ __launch_bounds__(512) void k_routing(
    const float* __restrict__ votes, float* __restrict__ out)
{
    __shared__ float v[8][32][16];
    __shared__ float logits[8][32];
    __shared__ float route[8][32];
    const int b = blockIdx.x, tid = threadIdx.x;
    const float* vb = votes + (size_t)b * 4096;
    for (int i = tid; i < 4096; i += 512) ((float*)v)[i] = vb[i];
    if (tid < 256) ((float*)logits)[tid] = 0.0f;
    __syncthreads();
    const int c = tid >> 4, a = tid & 15;
    float n2 = 0.0f;
    for (int it = 0; it < 3; ++it) {
        if (tid < 256) {
            const int r = tid >> 5, cc = tid & 31;
            const float l = logits[r][cc];
            float mx = l;
            #pragma unroll
            for (int m = 1; m < 32; m <<= 1) mx = fmaxf(mx, __shfl_xor(mx, m));
            const float e = __expf(l - mx);
            float sm = e;
            #pragma unroll
            for (int m = 1; m < 32; m <<= 1) sm += __shfl_xor(sm, m);
            route[r][cc] = e / sm;
        }
        __syncthreads();
        float pa = 0.0f;
        #pragma unroll
        for (int r = 0; r < 8; ++r) pa += route[r][c] * v[r][c][a];
        n2 = pa * pa;
        #pragma unroll
        for (int m = 1; m < 16; m <<= 1) n2 += __shfl_xor(n2, m);
        const float nrm = sqrtf(n2);
        const float av = pa * (nrm / (0.5f + n2));
        if (it < 2) {
            #pragma unroll
            for (int r = 0; r < 8; ++r) {
                float u = v[r][c][a] * av;
                #pragma unroll
                for (int m = 1; m < 16; m <<= 1) u += __shfl_xor(u, m);
                if (a == 0) logits[r][c] += u;
            }
        }
        __syncthreads();
    }
    if (a == 0) out[b * 32 + c] = n2 / (0.5f + n2);
}

// ---------------------------------------------------------------------------
static void launch_scan(const float* Z, const float* wf, const float* wb,
                        float* ob, int bt, float* hx, int* fl, hipStream_t stream)
{
    void* args[] = {(void*)&Z, (void*)&wf, (void*)&wb, (void*)&ob,
                    (void*)&bt, (void*)&hx, (void*)&fl};
    if (hipLaunchCooperativeKernel((const void*)k_scan5, dim3(256), dim3(512),
                                   args, 0, stream) != hipSuccess)
        k_scan5<<<dim3(256), 512, 0, stream>>>(Z, wf, wb, ob, bt, hx, fl);
}

extern "C" void kernel_launch(void* const* d_in, const int* in_sizes, int n_in,
                              void* d_out, int out_size, void* d_ws, size_t ws_size,
                              hipStream_t stream) {
    (void)in_sizes; (void)n_in; (void)out_size; (void)ws_size;
    const int*   tokens  = (const int*)d_in[0];
    const float* emb     = (const float*)d_in[2];
    const float* w_ih_f0 = (const float*)d_in[3];
    const float* w_hh_f0 = (const float*)d_in[4];
    const float* b_f0    = (const float*)d_in[5];
    const float* w_ih_b0 = (const float*)d_in[6];
    const float* w_hh_b0 = (const float*)d_in[7];
    const float* b_b0    = (const float*)d_in[8];
    const float* w_ih_f1 = (const float*)d_in[9];
    const float* w_hh_f1 = (const float*)d_in[10];
    const float* b_f1    = (const float*)d_in[11];
    const float* w_ih_b1 = (const float*)d_in[12];
    const float* w_hh_b1 = (const float*)d_in[13];
    const float* b_b1    = (const float*)d_in[14];
    const float* ws1     = (const float*)d_in[15];
    const float* ws2     = (const float*)d_in[16];
    const float* caps    = (const float*)d_in[17];

    float* wsf  = (float*)d_ws;
    float* Wt   = wsf;                          //  4 * 262144
    float* Z    = Wt   + 4 * 262144;            //  8192*2048
    float* x1   = Z    + 16777216;              //  8192*512
    float* outp = x1   + 4194304;               //  8192*512
    float* hbar = outp + 4194304;               //  8192*128
    float* sent = hbar + 1048576;               //  128*8*512
    float* vote = sent + 524288;                //  128*8*512
    float* hx   = vote + 524288;                //  2*2*32*1024 = 131072
    int*   flags = (int*)(hx + 131072);         //  2 * 4096 ints
    float* out  = (float*)d_out;

    // 0. zero sync flags (every launch; replays don't re-poison)
    k_zero<<<dim3(32), 256, 0, stream>>>(flags, 8192);
    // 1. transpose recurrent weights
    k_transpose<<<dim3(32, 8, 4), dim3(32, 8), 0, stream>>>(w_hh_f0, w_hh_b0, w_hh_f1, w_hh_b1, Wt);
    // 2. layer-0 input projection (embedding gather fused)
    k_gemm<<<dim3(64, 16, 1), 256, 0, stream>>>(
        emb, 300, tokens, w_ih_f0, w_ih_b0, 1024, 300, b_f0, b_b0,
        Z, 2048, 300, 1, 0, 0LL, 0LL, 0LL);
    // 3. layer-0 scan -> x1 [t*128+b][512]
    launch_scan(Z, Wt, Wt + 262144, x1, 0, hx, flags, stream);
    // 4. layer-1 input projection
    k_gemm<<<dim3(64, 16, 1), 256, 0, stream>>>(
        x1, 512, (const int*)nullptr, w_ih_f1, w_ih_b1, 1024, 512, b_f1, b_b1,
        Z, 2048, 512, 1, 0, 0LL, 0LL, 0LL);
    // 5. layer-1 scan -> outp [b*64+t][512]
    launch_scan(Z, Wt + 2 * 262144, Wt + 3 * 262144, outp, 1, hx, flags + 4096, stream);
    // 6. hbar = tanh(outp @ ws1^T)
    k_gemm<<<dim3(64, 1, 1), 256, 0, stream>>>(
        outp, 512, (const int*)nullptr, ws1, (const float*)nullptr, 1 << 30, 512,
        (const float*)nullptr, (const float*)nullptr,
        hbar, 128, 512, 1, 1, 0LL, 0LL, 0LL);
    // 7. attention + sent
    k_attnpool<<<dim3(128), 256, 0, stream>>>(hbar, outp, ws2, sent);
    // 8. votes
    k_gemm<<<dim3(1, 4, 8), 256, 0, stream>>>(
        sent, 4096, (const int*)nullptr, caps, (const float*)nullptr, 1 << 30, 512,
        (const float*)nullptr, (const float*)nullptr,
        vote, 4096, 512, 0, 0, 512LL, 262144LL, 512LL);
    // 9. routing
    k_routing<<<dim3(128), 512, 0, stream>>>(vote, out);
}

// Round 9
// 868.631 us; speedup vs baseline: 1.4428x; 1.4428x over previous
//
#include <hip/hip_runtime.h>
#include <hip/hip_bf16.h>

// ---------------------------------------------------------------------------
// CapsuleNetwork: embedding -> 2-layer BiLSTM -> attn pooling -> routing
// Round 8: scan reverted to R6 k_scan4 (best, 289us). Projection GEMMs moved
// to bf16x3 split-precision MFMA (hi/lo bf16, 3x mfma_f32_16x16x32_bf16,
// ~2^-17 rel error). bf16 scratch aliases outp/hbar region (dead until later).
// B=128 T=64 E=300 H=256 DA=128 R=8 SC=32 AT=16
// ---------------------------------------------------------------------------

typedef __attribute__((ext_vector_type(8))) short bf16x8;
typedef __attribute__((ext_vector_type(4))) float f32x4;

__device__ __forceinline__ float sigf(float x) { return 1.0f / (1.0f + __expf(-x)); }
__device__ __forceinline__ float tanhf_fast(float x) { return 1.0f - 2.0f / (__expf(2.0f * x) + 1.0f); }

#define DPPF(v, ctrl) __int_as_float(__builtin_amdgcn_update_dpp(0, __float_as_int(v), ctrl, 0xF, 0xF, true))

// ---------------- transpose w_hh [1024][256] -> Wt [256][1024] -------------
__global__ void k_transpose(const float* __restrict__ w0, const float* __restrict__ w1,
                            const float* __restrict__ w2, const float* __restrict__ w3,
                            float* __restrict__ wt)
{
    __shared__ float tile[32][33];
    const float* W = (blockIdx.z == 0) ? w0 : (blockIdx.z == 1) ? w1 : (blockIdx.z == 2) ? w2 : w3;
    float* Wt = wt + (size_t)blockIdx.z * 256 * 1024;
    const int j0 = blockIdx.x * 32, k0 = blockIdx.y * 32;
    const int tx = threadIdx.x, ty = threadIdx.y;  // (32,8)
    #pragma unroll
    for (int i = 0; i < 32; i += 8)
        tile[ty + i][tx] = W[(size_t)(j0 + ty + i) * 256 + (k0 + tx)];
    __syncthreads();
    #pragma unroll
    for (int i = 0; i < 32; i += 8)
        Wt[(size_t)(k0 + ty + i) * 1024 + (j0 + tx)] = tile[tx][ty + i];
}

// ---------------- zero sync flags ------------------------------------------
__global__ void k_zero(int* __restrict__ p, int n)
{
    const int i = blockIdx.x * blockDim.x + threadIdx.x;
    if (i < n) p[i] = 0;
}

// ---------------- fp32 -> (hi,lo) bf16 split, optional gather + K-pad ------
// dst rows r: src row = tokens ? tokens[(r&127)*64 + (r>>7)] : r.
// k >= Kin zero-padded. One thread = 4 consecutive k.
__global__ void k_split(const float* __restrict__ src, const int* __restrict__ tokens,
                        int Kin, int Kp, unsigned short* __restrict__ hi,
                        unsigned short* __restrict__ lo)
{
    const int i4 = (blockIdx.x * 256 + threadIdx.x) * 4;
    const int r = i4 / Kp;
    const int k = i4 - r * Kp;
    const float* srow;
    if (tokens) {
        const int t = r >> 7, b = r & 127;
        srow = src + (size_t)tokens[b * 64 + t] * Kin;
    } else {
        srow = src + (size_t)r * Kin;
    }
    float e[4];
    if (k + 4 <= Kin) {
        const float4 v = *(const float4*)(srow + k);
        e[0] = v.x; e[1] = v.y; e[2] = v.z; e[3] = v.w;
    } else {
        #pragma unroll
        for (int j = 0; j < 4; ++j) e[j] = (k + j < Kin) ? srow[k + j] : 0.0f;
    }
    ushort4 hv, lv;
    #pragma unroll
    for (int j = 0; j < 4; ++j) {
        __hip_bfloat16 bh = __float2bfloat16(e[j]);
        const float fh = __bfloat162float(bh);
        __hip_bfloat16 bl = __float2bfloat16(e[j] - fh);
        ((unsigned short*)&hv)[j] = *(unsigned short*)&bh;
        ((unsigned short*)&lv)[j] = *(unsigned short*)&bl;
    }
    *(ushort4*)&hi[(size_t)r * Kp + k] = hv;
    *(ushort4*)&lo[(size_t)r * Kp + k] = lv;
}

// ---------------- bf16x3 MFMA GEMM -----------------------------------------
// C[m][n] = sum_k A[m,k]*W[n,k] + bias[n], A/W given as (hi,lo) bf16 pairs.
// 3 MFMAs per fragment: hi*hi + hi*lo + lo*hi  (lo*lo ~2^-18, dropped).
// Tile 128x128, 256 thr = 4 waves (2x2 of 64x64), 4x4 frags of 16x16x32.
// LDS stride 40 bf16 -> ds_read_b128 2-way bank aliasing (free).
// Fragment layouts (m89/m91-verified): A/B lane l: row/col = l&15, k-chunk
// (l>>4)*8 contiguous; C/D: col = l&15, row = (l>>4)*4 + reg.
__global__ __launch_bounds__(256) void k_mgemm(
    const unsigned short* __restrict__ Ahi, const unsigned short* __restrict__ Alo,
    const unsigned short* __restrict__ Whi, const unsigned short* __restrict__ Wlo,
    const float* __restrict__ bias0, const float* __restrict__ bias1, int nsplit,
    float* __restrict__ C, int ldc, int Kp)
{
    __shared__ unsigned short lAh[128 * 40];
    __shared__ unsigned short lAl[128 * 40];
    __shared__ unsigned short lBh[128 * 40];
    __shared__ unsigned short lBl[128 * 40];

    const int tid = threadIdx.x;
    const int m0 = blockIdx.x * 128;
    const int n0 = blockIdx.y * 128;
    const int w  = tid >> 6, l = tid & 63;
    const int wm = (w >> 1) * 64, wn = (w & 1) * 64;
    const int lr = l & 15, lk = (l >> 4) * 8;

    f32x4 acc[4][4];
    #pragma unroll
    for (int i = 0; i < 4; ++i)
        #pragma unroll
        for (int j = 0; j < 4; ++j)
            acc[i][j] = (f32x4){0.f, 0.f, 0.f, 0.f};

    for (int kt = 0; kt < Kp; kt += 32) {
        // ---- stage 4 tiles of 128x32 bf16 (2 chunks of 8 per thread/tile) ----
        #pragma unroll
        for (int p = 0; p < 2; ++p) {
            const int chunk = tid + p * 256;          // 0..511
            const int row = chunk >> 2;
            const int k8  = (chunk & 3) * 8;
            const size_t ga = (size_t)(m0 + row) * Kp + kt + k8;
            const size_t gb = (size_t)(n0 + row) * Kp + kt + k8;
            const int la = row * 40 + k8;
            *(bf16x8*)&lAh[la] = *(const bf16x8*)&Ahi[ga];
            *(bf16x8*)&lAl[la] = *(const bf16x8*)&Alo[ga];
            *(bf16x8*)&lBh[la] = *(const bf16x8*)&Whi[gb];
            *(bf16x8*)&lBl[la] = *(const bf16x8*)&Wlo[gb];
        }
        __syncthreads();
        // ---- load fragments ----
        bf16x8 ah[4], al[4], bh[4], bl[4];
        #pragma unroll
        for (int f = 0; f < 4; ++f) {
            const int ra = (wm + f * 16 + lr) * 40 + lk;
            const int rb = (wn + f * 16 + lr) * 40 + lk;
            ah[f] = *(const bf16x8*)&lAh[ra];
            al[f] = *(const bf16x8*)&lAl[ra];
            bh[f] = *(const bf16x8*)&lBh[rb];
            bl[f] = *(const bf16x8*)&lBl[rb];
        }
        // ---- 48 MFMAs ----
        #pragma unroll
        for (int fm = 0; fm < 4; ++fm)
            #pragma unroll
            for (int fn = 0; fn < 4; ++fn) {
                acc[fm][fn] = __builtin_amdgcn_mfma_f32_16x16x32_bf16(ah[fm], bh[fn], acc[fm][fn], 0, 0, 0);
                acc[fm][fn] = __builtin_amdgcn_mfma_f32_16x16x32_bf16(ah[fm], bl[fn], acc[fm][fn], 0, 0, 0);
                acc[fm][fn] = __builtin_amdgcn_mfma_f32_16x16x32_bf16(al[fm], bh[fn], acc[fm][fn], 0, 0, 0);
            }
        __syncthreads();
    }
    // ---- epilogue ----
    #pragma unroll
    for (int fm = 0; fm < 4; ++fm)
        #pragma unroll
        for (int fn = 0; fn < 4; ++fn) {
            const int col = n0 + wn + fn * 16 + lr;
            const float bv = (col < nsplit) ? (bias0 ? bias0[col] : 0.f)
                                            : (bias1 ? bias1[col - nsplit] : 0.f);
            #pragma unroll
            for (int j = 0; j < 4; ++j) {
                const int row = m0 + wm + fm * 16 + (l >> 4) * 4 + j;
                C[(size_t)row * ldc + col] = acc[fm][fn][j] + bv;
            }
        }
}

// ---------------- fp32 GEMM (R6) — used for hbar & votes only --------------
__global__ __launch_bounds__(256) void k_gemm(
    const float* __restrict__ A, int lda, const int* __restrict__ tokens,
    const float* __restrict__ W0, const float* __restrict__ W1, int nsplit, int ldw,
    const float* __restrict__ bias0, const float* __restrict__ bias1,
    float* __restrict__ C, int ldc, int K, int transb, int act_tanh,
    long long sA, long long sW, long long sC)
{
    __shared__ float As[32][128];
    __shared__ float Ws[32][128];
    A  += (size_t)blockIdx.z * (size_t)sA;
    W0 += (size_t)blockIdx.z * (size_t)sW;
    C  += (size_t)blockIdx.z * (size_t)sC;
    const int tid = threadIdx.x;
    const int m0 = blockIdx.x * 128;
    const int n0 = blockIdx.y * 128;

    const int srow = tid >> 1;
    const int kh   = (tid & 1) * 16;
    const int am = m0 + srow;
    const float* arow;
    if (tokens) {
        const int t = am >> 7, b = am & 127;
        arow = A + (size_t)tokens[b * 64 + t] * lda;
    } else {
        arow = A + (size_t)am * lda;
    }
    const int wn = n0 + srow;
    const float* wrow = (wn < nsplit) ? (W0 + (size_t)wn * ldw)
                                      : (W1 + (size_t)(wn - nsplit) * ldw);
    const int kw = tid >> 3;
    const int n8 = (tid & 7) * 16;

    const int tm4 = (tid & 15) * 4;
    const int tn4 = (tid >> 4) * 4;
    float acc[8][8] = {};
    float4 ra[4], rw[4];

    const int nt = (K + 31) / 32;

    #pragma unroll
    for (int j = 0; j < 4; ++j) {
        const int k = kh + j * 4;
        if (k + 3 < K) ra[j] = *(const float4*)(arow + k);
        else {
            float t0 = (k + 0 < K) ? arow[k + 0] : 0.f;
            float t1 = (k + 1 < K) ? arow[k + 1] : 0.f;
            float t2 = (k + 2 < K) ? arow[k + 2] : 0.f;
            float t3 = (k + 3 < K) ? arow[k + 3] : 0.f;
            ra[j] = make_float4(t0, t1, t2, t3);
        }
    }
    if (transb) {
        #pragma unroll
        for (int j = 0; j < 4; ++j) {
            const int k = kh + j * 4;
            if (k + 3 < K) rw[j] = *(const float4*)(wrow + k);
            else {
                float t0 = (k + 0 < K) ? wrow[k + 0] : 0.f;
                float t1 = (k + 1 < K) ? wrow[k + 1] : 0.f;
                float t2 = (k + 2 < K) ? wrow[k + 2] : 0.f;
                float t3 = (k + 3 < K) ? wrow[k + 3] : 0.f;
                rw[j] = make_float4(t0, t1, t2, t3);
            }
        }
    } else {
        const float* src = (kw < K) ? (W0 + (size_t)kw * ldw + n0 + n8) : W0;
        #pragma unroll
        for (int j = 0; j < 4; ++j)
            rw[j] = (kw < K) ? *(const float4*)(src + j * 4) : make_float4(0, 0, 0, 0);
    }

    for (int tile = 0; tile < nt; ++tile) {
        #pragma unroll
        for (int j = 0; j < 4; ++j) {
            As[kh + j * 4 + 0][srow] = ra[j].x;
            As[kh + j * 4 + 1][srow] = ra[j].y;
            As[kh + j * 4 + 2][srow] = ra[j].z;
            As[kh + j * 4 + 3][srow] = ra[j].w;
        }
        if (transb) {
            #pragma unroll
            for (int j = 0; j < 4; ++j) {
                Ws[kh + j * 4 + 0][srow] = rw[j].x;
                Ws[kh + j * 4 + 1][srow] = rw[j].y;
                Ws[kh + j * 4 + 2][srow] = rw[j].z;
                Ws[kh + j * 4 + 3][srow] = rw[j].w;
            }
        } else {
            #pragma unroll
            for (int j = 0; j < 4; ++j)
                *(float4*)&Ws[kw][n8 + j * 4] = rw[j];
        }
        __syncthreads();
        if (tile + 1 < nt) {
            const int kb = (tile + 1) * 32;
            #pragma unroll
            for (int j = 0; j < 4; ++j) {
                const int k = kb + kh + j * 4;
                if (k + 3 < K) ra[j] = *(const float4*)(arow + k);
                else {
                    float t0 = (k + 0 < K) ? arow[k + 0] : 0.f;
                    float t1 = (k + 1 < K) ? arow[k + 1] : 0.f;
                    float t2 = (k + 2 < K) ? arow[k + 2] : 0.f;
                    float t3 = (k + 3 < K) ? arow[k + 3] : 0.f;
                    ra[j] = make_float4(t0, t1, t2, t3);
                }
            }
            if (transb) {
                #pragma unroll
                for (int j = 0; j < 4; ++j) {
                    const int k = kb + kh + j * 4;
                    if (k + 3 < K) rw[j] = *(const float4*)(wrow + k);
                    else {
                        float t0 = (k + 0 < K) ? wrow[k + 0] : 0.f;
                        float t1 = (k + 1 < K) ? wrow[k + 1] : 0.f;
                        float t2 = (k + 2 < K) ? wrow[k + 2] : 0.f;
                        float t3 = (k + 3 < K) ? wrow[k + 3] : 0.f;
                        rw[j] = make_float4(t0, t1, t2, t3);
                    }
                }
            } else {
                const int k = kb + kw;
                const float* src = (k < K) ? (W0 + (size_t)k * ldw + n0 + n8) : W0;
                #pragma unroll
                for (int j = 0; j < 4; ++j)
                    rw[j] = (k < K) ? *(const float4*)(src + j * 4) : make_float4(0, 0, 0, 0);
            }
        }
        #pragma unroll 8
        for (int kk = 0; kk < 32; ++kk) {
            const float4 a0 = *(const float4*)&As[kk][tm4];
            const float4 a1 = *(const float4*)&As[kk][tm4 + 64];
            const float4 b0 = *(const float4*)&Ws[kk][tn4];
            const float4 b1 = *(const float4*)&Ws[kk][tn4 + 64];
            const float av[8] = {a0.x, a0.y, a0.z, a0.w, a1.x, a1.y, a1.z, a1.w};
            const float bv[8] = {b0.x, b0.y, b0.z, b0.w, b1.x, b1.y, b1.z, b1.w};
            #pragma unroll
            for (int i = 0; i < 8; ++i)
                #pragma unroll
                for (int j = 0; j < 8; ++j)
                    acc[i][j] += av[i] * bv[j];
        }
        __syncthreads();
    }
    const int half = (n0 >= nsplit) ? 1 : 0;
    const float* bp = half ? bias1 : bias0;
    const int nl = n0 - (half ? nsplit : 0);
    #pragma unroll
    for (int i = 0; i < 8; ++i) {
        const int row = m0 + tm4 + (i >> 2) * 64 + (i & 3);
        #pragma unroll
        for (int jh = 0; jh < 2; ++jh) {
            float v[4];
            #pragma unroll
            for (int j = 0; j < 4; ++j) {
                float x = acc[i][jh * 4 + j];
                if (bp) x += bp[nl + tn4 + jh * 64 + j];
                if (act_tanh) x = tanhf_fast(x);
                v[j] = x;
            }
            *(float4*)(C + (size_t)row * ldc + n0 + tn4 + jh * 64) =
                make_float4(v[0], v[1], v[2], v[3]);
        }
    }
}

// ---------------- full-chip BiLSTM scan (R6 k_scan4, best measured) --------
__global__ __launch_bounds__(512, 4) void k_scan4(
    const float* __restrict__ Zin, const float* __restrict__ WtF,
    const float* __restrict__ WtB, float* __restrict__ outbuf,
    int bt_layout, float* __restrict__ hx, int* __restrict__ flags, int bx_base)
{
    __shared__ __align__(16) float hbuf[1024];   // h, XOR-swizzled [k][4b]
    __shared__ float zbuf[512];                  // [4b][128 local cols]

    const int bx  = blockIdx.x + bx_base;
    const int dir = bx >> 8;
    const int s   = (bx & 255) >> 5;
    const int q   = bx & 31;
    const int tid = threadIdx.x;
    const int cg  = tid >> 3;          // 0..63 col group (2 cols)
    const int ks  = tid & 7;           // 0..7  k chunk (32 k)
    const float* __restrict__ Wt = dir ? WtB : WtF;

    const int gate    = cg >> 4;                    // 0..3
    const int wg      = cg & 15;                    // 0..15
    const int colbase = gate * 256 + s * 32 + wg * 2;
    float W[32][2];
    {
        const float* wp = Wt + (size_t)(ks * 32) * 1024 + colbase;
        #pragma unroll
        for (int i = 0; i < 32; ++i) {
            const float2 w2 = *(const float2*)(wp + (size_t)i * 1024);
            W[i][0] = w2.x; W[i][1] = w2.y;
        }
    }

    const int pb  = tid >> 5;          // batch 0..3   (phase2, tid<128)
    const int pd  = tid & 31;          // local dim
    const int dim = s * 32 + pd;
    const int gb  = q * 4 + pb;
    float c_state = 0.0f;
    const int fbase = (dir * 32 + q) * 64;

    for (int tt = 0; tt < 64; ++tt) {
        const int t = dir ? (63 - tt) : tt;
        float z0 = 0.f, z1 = 0.f, z2 = 0.f, z3 = 0.f;
        if (tid < 128) {
            const float* zr = Zin + (size_t)(t * 128 + gb) * 2048 + dir * 1024 + dim;
            z0 = zr[0]; z1 = zr[256]; z2 = zr[512]; z3 = zr[768];
        }
        if (tt > 0) {
            if (tid == 0) {
                while (__hip_atomic_load(&flags[fbase + tt - 1], __ATOMIC_RELAXED,
                                         __HIP_MEMORY_SCOPE_AGENT) < 8)
                    __builtin_amdgcn_s_sleep(1);
            }
            __syncthreads();
            {
                const float* hsrc = hx + ((((size_t)((tt - 1) & 1)) * 2 + dir) * 32 + q) * 1024;
                #pragma unroll
                for (int j = 0; j < 2; ++j) {
                    const int idx = j * 512 + tid;
                    const int b = idx & 3, d = (idx >> 2) & 255;
                    const float v = __hip_atomic_load(&hsrc[b * 256 + d], __ATOMIC_RELAXED,
                                                      __HIP_MEMORY_SCOPE_AGENT);
                    hbuf[((d << 2) ^ (((d >> 4) & 7) << 2)) + b] = v;
                }
            }
            __syncthreads();
            float acc[4][2] = {};
            #pragma unroll
            for (int i = 0; i < 32; ++i) {
                const int k = (ks << 5) + i;
                const float4 h4 = *(const float4*)&hbuf[(k << 2) ^ (((k >> 4) & 7) << 2)];
                acc[0][0] += h4.x * W[i][0]; acc[0][1] += h4.x * W[i][1];
                acc[1][0] += h4.y * W[i][0]; acc[1][1] += h4.y * W[i][1];
                acc[2][0] += h4.z * W[i][0]; acc[2][1] += h4.z * W[i][1];
                acc[3][0] += h4.w * W[i][0]; acc[3][1] += h4.w * W[i][1];
            }
            #pragma unroll
            for (int b = 0; b < 4; ++b)
                #pragma unroll
                for (int c = 0; c < 2; ++c) {
                    float v = acc[b][c];
                    v += DPPF(v, 0xB1);                  // xor 1
                    v += DPPF(v, 0x4E);                  // xor 2
                    v += DPPF(DPPF(v, 0x141), 0x1B);     // xor 4
                    acc[b][c] = v;
                }
            #pragma unroll
            for (int a = 0; a < 8; ++a)
                if (ks == a)
                    zbuf[(a >> 1) * 128 + gate * 32 + wg * 2 + (a & 1)] = acc[a >> 1][a & 1];
            __syncthreads();
        } else {
            zbuf[tid & 511] = 0.0f;
            __syncthreads();
        }
        if (tid < 128) {
            const float zi = zbuf[pb * 128 +      pd] + z0;
            const float zf = zbuf[pb * 128 + 32 + pd] + z1;
            const float zg = zbuf[pb * 128 + 64 + pd] + z2;
            const float zo = zbuf[pb * 128 + 96 + pd] + z3;
            c_state = sigf(zf) * c_state + sigf(zi) * tanhf_fast(zg);
            const float h = sigf(zo) * tanhf_fast(c_state);
            const int row = bt_layout ? (gb * 64 + t) : (t * 128 + gb);
            outbuf[(size_t)row * 512 + dir * 256 + dim] = h;
            __hip_atomic_store(
                &hx[(((size_t)(tt & 1)) * 2 + dir) * 32768 + (size_t)q * 1024 + pb * 256 + dim],
                h, __ATOMIC_RELAXED, __HIP_MEMORY_SCOPE_AGENT);
        }
        __syncthreads();
        if (tid == 0)
            __hip_atomic_fetch_add(&flags[fbase + tt], 1, __ATOMIC_RELAXED,
                                   __HIP_MEMORY_SCOPE_AGENT);
    }
}

// ---------------- attention pooling (unchanged) ----------------------------
__global__ __launch_bounds__(256) void k_attnpool(
    const float* __restrict__ hbar, const float* __restrict__ outp,
    const float* __restrict__ ws2, float* __restrict__ sent)
{
    __shared__ float hb[64][132];
    __shared__ float w2[8][128];
    __shared__ float att[8][64];
    const int b = blockIdx.x, tid = threadIdx.x;
    for (int i = tid; i < 1024; i += 256) ((float*)w2)[i] = ws2[i];
    const float* hsrc = hbar + (size_t)b * 64 * 128;
    for (int i = tid; i < 2048; i += 256) {
        const int row = i >> 5, d4 = (i & 31) << 2;
        *(float4*)&hb[row][d4] = *(const float4*)(hsrc + row * 128 + d4);
    }
    __syncthreads();
    for (int p = tid; p < 512; p += 256) {
        const int r = p >> 6, t = p & 63;
        float s = 0.0f;
        #pragma unroll 8
        for (int d = 0; d < 128; d += 4) {
            const float4 x = *(const float4*)&hb[t][d];
            const float4 y = *(const float4*)&w2[r][d];
            s += x.x * y.x + x.y * y.y + x.z * y.z + x.w * y.w;
        }
        att[r][t] = s;
    }
    __syncthreads();
    const float* ob = outp + (size_t)b * 64 * 512;
    float s0[8] = {}, s1[8] = {};
    for (int t = 0; t < 64; ++t) {
        const float v0 = ob[t * 512 + tid];
        const float v1 = ob[t * 512 + 256 + tid];
        #pragma unroll
        for (int r = 0; r < 8; ++r) {
            const float a = att[r][t];
            s0[r] += a * v0; s1[r] += a * v1;
        }
    }
    #pragma unroll
    for (int r = 0; r < 8; ++r) {
        sent[((size_t)b * 8 + r) * 512 + tid]       = s0[r];
        sent[((size_t)b * 8 + r) * 512 + 256 + tid] = s1[r];
    }
}

// ---------------- dynamic routing (unchanged) ------------------------------
__global__ __launch_bounds__(512) void k_routing(
    const float* __restrict__ votes, float* __restrict__ out)
{
    __shared__ float v[8][32][16];
    __shared__ float logits[8][32];
    __shared__ float route[8][32];
    const int b = blockIdx.x, tid = threadIdx.x;
    const float* vb = votes + (size_t)b * 4096;
    for (int i = tid; i < 4096; i += 512) ((float*)v)[i] = vb[i];
    if (tid < 256) ((float*)logits)[tid] = 0.0f;
    __syncthreads();
    const int c = tid >> 4, a = tid & 15;
    float n2 = 0.0f;
    for (int it = 0; it < 3; ++it) {
        if (tid < 256) {
            const int r = tid >> 5, cc = tid & 31;
            const float l = logits[r][cc];
            float mx = l;
            #pragma unroll
            for (int m = 1; m < 32; m <<= 1) mx = fmaxf(mx, __shfl_xor(mx, m));
            const float e = __expf(l - mx);
            float sm = e;
            #pragma unroll
            for (int m = 1; m < 32; m <<= 1) sm += __shfl_xor(sm, m);
            route[r][cc] = e / sm;
        }
        __syncthreads();
        float pa = 0.0f;
        #pragma unroll
        for (int r = 0; r < 8; ++r) pa += route[r][c] * v[r][c][a];
        n2 = pa * pa;
        #pragma unroll
        for (int m = 1; m < 16; m <<= 1) n2 += __shfl_xor(n2, m);
        const float nrm = sqrtf(n2);
        const float av = pa * (nrm / (0.5f + n2));
        if (it < 2) {
            #pragma unroll
            for (int r = 0; r < 8; ++r) {
                float u = v[r][c][a] * av;
                #pragma unroll
                for (int m = 1; m < 16; m <<= 1) u += __shfl_xor(u, m);
                if (a == 0) logits[r][c] += u;
            }
        }
        __syncthreads();
    }
    if (a == 0) out[b * 32 + c] = n2 / (0.5f + n2);
}

// ---------------------------------------------------------------------------
static void launch_scan(const float* Z, const float* wf, const float* wb,
                        float* ob, int bt, float* hx, int* fl, hipStream_t stream)
{
    int base0 = 0;
    void* args[] = {(void*)&Z, (void*)&wf, (void*)&wb, (void*)&ob,
                    (void*)&bt, (void*)&hx, (void*)&fl, (void*)&base0};
    if (hipLaunchCooperativeKernel((const void*)k_scan4, dim3(512), dim3(512),
                                   args, 0, stream) != hipSuccess) {
        k_scan4<<<dim3(256), 512, 0, stream>>>(Z, wf, wb, ob, bt, hx, fl, 0);
        k_scan4<<<dim3(256), 512, 0, stream>>>(Z, wf, wb, ob, bt, hx, fl, 256);
    }
}

extern "C" void kernel_launch(void* const* d_in, const int* in_sizes, int n_in,
                              void* d_out, int out_size, void* d_ws, size_t ws_size,
                              hipStream_t stream) {
    (void)in_sizes; (void)n_in; (void)out_size; (void)ws_size;
    const int*   tokens  = (const int*)d_in[0];
    const float* emb     = (const float*)d_in[2];
    const float* w_ih_f0 = (const float*)d_in[3];
    const float* w_hh_f0 = (const float*)d_in[4];
    const float* b_f0    = (const float*)d_in[5];
    const float* w_ih_b0 = (const float*)d_in[6];
    const float* w_hh_b0 = (const float*)d_in[7];
    const float* b_b0    = (const float*)d_in[8];
    const float* w_ih_f1 = (const float*)d_in[9];
    const float* w_hh_f1 = (const float*)d_in[10];
    const float* b_f1    = (const float*)d_in[11];
    const float* w_ih_b1 = (const float*)d_in[12];
    const float* w_hh_b1 = (const float*)d_in[13];
    const float* b_b1    = (const float*)d_in[14];
    const float* ws1     = (const float*)d_in[15];
    const float* ws2     = (const float*)d_in[16];
    const float* caps    = (const float*)d_in[17];

    float* wsf  = (float*)d_ws;
    float* Wt   = wsf;                          //  4 * 262144
    float* Z    = Wt   + 4 * 262144;            //  8192*2048
    float* x1   = Z    + 16777216;              //  8192*512
    float* outp = x1   + 4194304;               //  8192*512
    float* hbar = outp + 4194304;               //  8192*128
    float* sent = hbar + 1048576;               //  128*8*512
    float* vote = sent + 524288;                //  128*8*512
    float* hx   = vote + 524288;                //  2*2*32*1024 = 131072
    int*   flags = (int*)(hx + 131072);         //  2 * 4096 ints
    float* out  = (float*)d_out;

    // bf16 split scratch aliases [outp, hbar) (5,242,880 f = 10,485,760 bf16).
    // L0 (13.1MB) / L1 (21MB, exact fit) groups are dead before outp/hbar are
    // written (scan1 step 7 / hbar step 8).
    unsigned short* bs = (unsigned short*)outp;
    // layer-0 (Kp=320):
    unsigned short* Ahi0 = bs;                       // 8192*320
    unsigned short* Alo0 = Ahi0 + 8192 * 320;
    unsigned short* Whi0 = Alo0 + 8192 * 320;        // 2048*320
    unsigned short* Wlo0 = Whi0 + 2048 * 320;
    // layer-1 (Kp=512):
    unsigned short* Ahi1 = bs;                       // 8192*512
    unsigned short* Alo1 = Ahi1 + 8192 * 512;
    unsigned short* Whi1 = Alo1 + 8192 * 512;        // 2048*512
    unsigned short* Wlo1 = Whi1 + 2048 * 512;

    // 0. zero sync flags (every launch; replays don't re-poison)
    k_zero<<<dim3(32), 256, 0, stream>>>(flags, 8192);
    // 1. transpose recurrent weights
    k_transpose<<<dim3(32, 8, 4), dim3(32, 8), 0, stream>>>(w_hh_f0, w_hh_b0, w_hh_f1, w_hh_b1, Wt);
    // 2. split layer-0 operands to (hi,lo) bf16
    k_split<<<dim3(2560), 256, 0, stream>>>(emb, tokens, 300, 320, Ahi0, Alo0);          // gather
    k_split<<<dim3(320),  256, 0, stream>>>(w_ih_f0, (const int*)nullptr, 300, 320, Whi0, Wlo0);
    k_split<<<dim3(320),  256, 0, stream>>>(w_ih_b0, (const int*)nullptr, 300, 320,
                                            Whi0 + 1024 * 320, Wlo0 + 1024 * 320);
    // 3. layer-0 projection (bf16x3 MFMA) -> Z
    k_mgemm<<<dim3(64, 16), 256, 0, stream>>>(Ahi0, Alo0, Whi0, Wlo0, b_f0, b_b0, 1024,
                                              Z, 2048, 320);
    // 4. layer-0 scan -> x1 [t*128+b][512]
    launch_scan(Z, Wt, Wt + 262144, x1, 0, hx, flags, stream);
    // 5. split layer-1 operands
    k_split<<<dim3(4096), 256, 0, stream>>>(x1, (const int*)nullptr, 512, 512, Ahi1, Alo1);
    k_split<<<dim3(512),  256, 0, stream>>>(w_ih_f1, (const int*)nullptr, 512, 512, Whi1, Wlo1);
    k_split<<<dim3(512),  256, 0, stream>>>(w_ih_b1, (const int*)nullptr, 512, 512,
                                            Whi1 + 1024 * 512, Wlo1 + 1024 * 512);
    // 6. layer-1 projection (bf16x3 MFMA) -> Z
    k_mgemm<<<dim3(64, 16), 256, 0, stream>>>(Ahi1, Alo1, Whi1, Wlo1, b_f1, b_b1, 1024,
                                              Z, 2048, 512);
    // 7. layer-1 scan -> outp [b*64+t][512]  (clobbers bf16 scratch: dead)
    launch_scan(Z, Wt + 2 * 262144, Wt + 3 * 262144, outp, 1, hx, flags + 4096, stream);
    // 8. hbar = tanh(outp @ ws1^T)
    k_gemm<<<dim3(64, 1, 1), 256, 0, stream>>>(
        outp, 512, (const int*)nullptr, ws1, (const float*)nullptr, 1 << 30, 512,
        (const float*)nullptr, (const float*)nullptr,
        hbar, 128, 512, 1, 1, 0LL, 0LL, 0LL);
    // 9. attention + sent
    k_attnpool<<<dim3(128), 256, 0, stream>>>(hbar, outp, ws2, sent);
    // 10. votes
    k_gemm<<<dim3(1, 4, 8), 256, 0, stream>>>(
        sent, 4096, (const int*)nullptr, caps, (const float*)nullptr, 1 << 30, 512,
        (const float*)nullptr, (const float*)nullptr,
        vote, 4096, 512, 0, 0, 512LL, 262144LL, 512LL);
    // 11. routing
    k_routing<<<dim3(128), 512, 0, stream>>>(vote, out);
}